// Round 7
// baseline (503.392 us; speedup 1.0000x reference)
//
#include <hip/hip_runtime.h>

// ---------------------------------------------------------------------------
// Algebraic collapse: the scan is linear & batch-independent.
//   m_{t+1} = A m_t + beta,  A[(j,e),(i,d)] = gate[i,j]*W[i,j,e,d]
//   out = inp @ Weff^T + beff,  Weff = Wpost * S * Wpre,
//   S = (A^10)[block15, block0],  c = (sum_{k<10} A^k beta)[block15]
// QT [144 x 2048] iterate in split-bf16 (hi+lo), fp32 MFMA accumulate.
// Round 7: A-read-once steps. One block per n-tile (128 blocks) x 768 thr
// (12 waves = 3 m-groups x 4 K-chunks of 512); full M inside the block so
// A is fetched exactly once per step (33.5 MB vs R6's 100 MB); LDS K-reduce,
// fused beta/split epilogue. Tail fused to one kernel via
// Weff[o,:] = (Wpost[o,:]*S)*Wpre (u in LDS, no global T1). 12 dispatches.
// ---------------------------------------------------------------------------

typedef __bf16 bf16x8 __attribute__((ext_vector_type(8)));
typedef float f32x4 __attribute__((ext_vector_type(4)));

__device__ __forceinline__ unsigned short f2bf(float x) {
  unsigned int u = __float_as_uint(x);
  u += 0x7FFFu + ((u >> 16) & 1u);   // round-to-nearest-even
  return (unsigned short)(u >> 16);
}
__device__ __forceinline__ float bf2f(unsigned short s) {
  return __uint_as_float(((unsigned int)s) << 16);
}
__device__ __forceinline__ bf16x8 ldg8(const unsigned short* p) {
  return __builtin_bit_cast(bf16x8, *(const uint4*)p);
}
__device__ __forceinline__ f32x4 mfma16(bf16x8 a, bf16x8 b, f32x4 c) {
  return __builtin_amdgcn_mfma_f32_16x16x32_bf16(a, b, c, 0, 0, 0);
}

#define ND 2048   // num*dim
#define MT 144    // iterate rows (129 used: 128 propagator + 1 bias; rest 0)

// ---------------------------------------------------------------------------
// prep: blocks 0..2047 build split-A; 2048..3071 split inp; 3072..3135 build
// Q1 (exact step t=1) directly from W + beta row. All independent.
// ---------------------------------------------------------------------------
__global__ __launch_bounds__(256) void prep_kernel(
    const float* __restrict__ W, const float* __restrict__ life,
    const float* __restrict__ inp, const float* __restrict__ bl,
    unsigned short* __restrict__ Ahi, unsigned short* __restrict__ Alo,
    unsigned short* __restrict__ Ihi, unsigned short* __restrict__ Ilo,
    unsigned short* __restrict__ Qhi, unsigned short* __restrict__ Qlo,
    float* __restrict__ beta) {
  const int b = blockIdx.x, t = threadIdx.x;
  if (b < 2048) {
    long base = ((long)b * 256 + t) * 8;
    int n = (int)(base >> 11), k = (int)(base & 2047);
    int j = n >> 7, e = n & 127, i = k >> 7, d0 = k & 127;
    float gv = life[i * 16 + j];
    float gate = gv > 0.f ? gv : 0.f;
    const float* src = W + ((i * 16 + j) * 16384 + e * 128 + d0);
    float4 a = *(const float4*)src, b4 = *(const float4*)(src + 4);
    float vals[8] = {a.x, a.y, a.z, a.w, b4.x, b4.y, b4.z, b4.w};
    union { unsigned short u[8]; uint4 v; } ph, pl;
#pragma unroll
    for (int x = 0; x < 8; ++x) {
      float v = gate * vals[x];
      unsigned short h = f2bf(v);
      ph.u[x] = h;
      pl.u[x] = f2bf(v - bf2f(h));
    }
    *(uint4*)(Ahi + base) = ph.v;
    *(uint4*)(Alo + base) = pl.v;
  } else if (b < 3072) {
    long base = ((long)(b - 2048) * 256 + t) * 8;
    float4 a = *(const float4*)(inp + base), b4 = *(const float4*)(inp + base + 4);
    float vals[8] = {a.x, a.y, a.z, a.w, b4.x, b4.y, b4.z, b4.w};
    union { unsigned short u[8]; uint4 v; } ph, pl;
#pragma unroll
    for (int x = 0; x < 8; ++x) {
      unsigned short h = f2bf(vals[x]);
      ph.u[x] = h;
      pl.u[x] = f2bf(vals[x] - bf2f(h));
    }
    *(uint4*)(Ihi + base) = ph.v;
    *(uint4*)(Ilo + base) = pl.v;
  } else {
    // Q1[c][n] = gate[0,j]*W[0,j,e,c] (exact t=1), c<128; row 128 = beta.
    const int nb = b - 3072;                 // n-range [nb*32, nb*32+32)
    {
      int n = nb * 32 + (t >> 3);
      int c0 = (t & 7) * 16;
      int j = n >> 7, e = n & 127;
      float gv = life[j];
      float gate = gv > 0.f ? gv : 0.f;
      const float* src = W + (j * 16384 + e * 128 + c0);
      float4 w0 = *(const float4*)src, w1 = *(const float4*)(src + 4);
      float4 w2 = *(const float4*)(src + 8), w3 = *(const float4*)(src + 12);
      float vals[16] = {w0.x, w0.y, w0.z, w0.w, w1.x, w1.y, w1.z, w1.w,
                        w2.x, w2.y, w2.z, w2.w, w3.x, w3.y, w3.z, w3.w};
#pragma unroll
      for (int x = 0; x < 16; ++x) {
        float v = gate * vals[x];
        unsigned short h = f2bf(v);
        Qhi[(c0 + x) * ND + n] = h;
        Qlo[(c0 + x) * ND + n] = f2bf(v - bf2f(h));
      }
    }
    if (t < 32) {
      int n = nb * 32 + t;
      int j = n >> 7, e = n & 127;
      float s = 0.f;
#pragma unroll
      for (int i = 0; i < 16; ++i) {
        float gv = life[i * 16 + j];
        float g = gv > 0.f ? gv : 0.f;
        s += g * bl[(i * 16 + j) * 128 + e];
      }
      beta[n] = s;
      unsigned short h = f2bf(s);
      Qhi[128 * ND + n] = h;
      Qlo[128 * ND + n] = f2bf(s - bf2f(h));
    }
    for (int idx = t; idx < 480; idx += 256) {
      int r = 129 + (idx >> 5), n = nb * 32 + (idx & 31);
      Qhi[r * ND + n] = 0;
      Qlo[r * ND + n] = 0;
    }
  }
}

// ---------------------------------------------------------------------------
// Full step: 128 blocks (one per 16-wide n-tile) x 768 thr. Wave wv:
// m-group mg = wv>>2 (rows [mg*48,+48), 3 m-tiles), K-chunk kq = wv&3
// ([kq*512,+512), 16 iters). A is read once per step (full M per block).
// Cross-K LDS reduce; epilogue fuses +beta (row 128) + split-bf16 write.
// ---------------------------------------------------------------------------
__global__ __launch_bounds__(768) void step_full(
    const unsigned short* __restrict__ Ahi, const unsigned short* __restrict__ Alo,
    const unsigned short* __restrict__ qh, const unsigned short* __restrict__ ql,
    const float* __restrict__ beta,
    unsigned short* __restrict__ oh, unsigned short* __restrict__ ol) {
  __shared__ float red[12][3][256];   // [wave][m-tile][ml*16 + nl]
  const int t = threadIdx.x;
  const int wv = t >> 6, lane = t & 63;
  const int r16 = lane & 15, q = lane >> 4;
  const int mg = wv >> 2, kq = wv & 3;
  const int n0 = blockIdx.x * 16;
  const int kbase = kq * 512 + q * 8;

  const unsigned short* pBh = Ahi + (n0 + r16) * ND + kbase;
  const unsigned short* pBl = Alo + (n0 + r16) * ND + kbase;
  const int m0 = mg * 48 + r16;
  const unsigned short* pAh = qh + m0 * ND + kbase;
  const unsigned short* pAl = ql + m0 * ND + kbase;

  f32x4 acc[3];
  acc[0] = acc[1] = acc[2] = (f32x4){0.f, 0.f, 0.f, 0.f};

#pragma unroll 2
  for (int it = 0; it < 16; ++it) {
    const int ko = it * 32;
    bf16x8 bh = ldg8(pBh + ko), bl = ldg8(pBl + ko);
    bf16x8 a0h = ldg8(pAh + ko), a0l = ldg8(pAl + ko);
    bf16x8 a1h = ldg8(pAh + 16 * ND + ko), a1l = ldg8(pAl + 16 * ND + ko);
    bf16x8 a2h = ldg8(pAh + 32 * ND + ko), a2l = ldg8(pAl + 32 * ND + ko);

    acc[0] = mfma16(a0h, bh, acc[0]);
    acc[0] = mfma16(a0l, bh, acc[0]);
    acc[0] = mfma16(a0h, bl, acc[0]);
    acc[1] = mfma16(a1h, bh, acc[1]);
    acc[1] = mfma16(a1l, bh, acc[1]);
    acc[1] = mfma16(a1h, bl, acc[1]);
    acc[2] = mfma16(a2h, bh, acc[2]);
    acc[2] = mfma16(a2l, bh, acc[2]);
    acc[2] = mfma16(a2h, bl, acc[2]);
  }

#pragma unroll
  for (int mt = 0; mt < 3; ++mt)
#pragma unroll
    for (int r = 0; r < 4; ++r)
      red[wv][mt][(q * 4 + r) * 16 + r16] = acc[mt][r];
  __syncthreads();

  // 2304 outputs = 768 thr x 3
#pragma unroll
  for (int rr = 0; rr < 3; ++rr) {
    const int x = t + rr * 768;
    const int m = x >> 4, nl = x & 15;
    const int mgx = m / 48;                 // 48 = 3*16, so m&15 == ml
    const int mtl = (m - mgx * 48) >> 4;
    const int li = (m & 15) * 16 + nl;
    float v = red[mgx * 4 + 0][mtl][li] + red[mgx * 4 + 1][mtl][li] +
              red[mgx * 4 + 2][mtl][li] + red[mgx * 4 + 3][mtl][li];
    const int n = n0 + nl;
    if (m == 128) v += beta[n];
    unsigned short h = f2bf(v);
    oh[m * ND + n] = h;
    ol[m * ND + n] = f2bf(v - bf2f(h));
  }
}

// ---------------------------------------------------------------------------
// Last step (t=10): only n in [1920,2048) is read downstream. grid (8 nb,
// 9 mt) x 256 thr; wave wv owns K-chunk of 512, ONE m-tile. LDS reduce,
// then write S[e,d] fp32 (m<128) / cvec[e]=v+beta (m==128) directly.
// ---------------------------------------------------------------------------
__global__ __launch_bounds__(256) void step_last(
    const unsigned short* __restrict__ Ahi, const unsigned short* __restrict__ Alo,
    const unsigned short* __restrict__ qh, const unsigned short* __restrict__ ql,
    const float* __restrict__ beta,
    float* __restrict__ S, float* __restrict__ cvec) {
  __shared__ float red[4][256];
  const int t = threadIdx.x;
  const int wv = t >> 6, lane = t & 63;
  const int r16 = lane & 15, q = lane >> 4;
  const int nb = blockIdx.x + 120, mt = blockIdx.y;
  const int n0 = nb * 16;
  const int kbase = wv * 512 + q * 8;

  const unsigned short* pBh = Ahi + (n0 + r16) * ND + kbase;
  const unsigned short* pBl = Alo + (n0 + r16) * ND + kbase;
  const int m0 = mt * 16 + r16;
  const unsigned short* pAh = qh + m0 * ND + kbase;
  const unsigned short* pAl = ql + m0 * ND + kbase;

  f32x4 acc = (f32x4){0.f, 0.f, 0.f, 0.f};
#pragma unroll 4
  for (int it = 0; it < 16; ++it) {
    const int ko = it * 32;
    bf16x8 bh = ldg8(pBh + ko), bl = ldg8(pBl + ko);
    bf16x8 ah = ldg8(pAh + ko), al = ldg8(pAl + ko);
    acc = mfma16(ah, bh, acc);
    acc = mfma16(al, bh, acc);
    acc = mfma16(ah, bl, acc);
  }
#pragma unroll
  for (int r = 0; r < 4; ++r)
    red[wv][(q * 4 + r) * 16 + r16] = acc[r];
  __syncthreads();

  {
    const int ml = t >> 4, nl = t & 15;
    const int li = ml * 16 + nl;
    float v = red[0][li] + red[1][li] + red[2][li] + red[3][li];
    const int m = mt * 16 + ml;
    const int n = n0 + nl;
    const int e = n - 1920;
    if (m < 128) S[e * 128 + m] = v;                 // d = m
    else if (m == 128) cvec[e] = v + beta[n];
  }
}

// ---------------------------------------------------------------------------
// Fused tail: blocks 0..511 compute Weff row o via u = Wpost[o,:]*S (LDS),
// then Weff[o,ic] = sum_d u[d]*Wpre[d,ic] (coalesced), split-bf16 write.
// Block 512: g = cvec + S*bpre, then beff = bpost + Wpost*g.
// ---------------------------------------------------------------------------
__global__ __launch_bounds__(256) void tail_fused(
    const float* __restrict__ S, const float* __restrict__ cvec,
    const float* __restrict__ Wpre, const float* __restrict__ bpre,
    const float* __restrict__ Wpost, const float* __restrict__ bpost,
    unsigned short* __restrict__ Whi, unsigned short* __restrict__ Wlo,
    float* __restrict__ beff) {
  __shared__ float part[256];
  __shared__ float uv[128];
  const int b = blockIdx.x, t = threadIdx.x;
  if (b < 512) {
    {
      const int d = t & 127, half = t >> 7;
      float s = 0.f;
      const int e0 = half * 64;
      for (int e = e0; e < e0 + 64; ++e)
        s += Wpost[b * 128 + e] * S[e * 128 + d];
      part[t] = s;
    }
    __syncthreads();
    if (t < 128) uv[t] = part[t] + part[t + 128];
    __syncthreads();
    float s0 = 0.f, s1 = 0.f;
    for (int d = 0; d < 128; ++d) {
      const float ud = uv[d];
      s0 += ud * Wpre[d * 512 + t];
      s1 += ud * Wpre[d * 512 + t + 256];
    }
    unsigned short h0 = f2bf(s0), h1 = f2bf(s1);
    Whi[b * 512 + t] = h0;
    Wlo[b * 512 + t] = f2bf(s0 - bf2f(h0));
    Whi[b * 512 + t + 256] = h1;
    Wlo[b * 512 + t + 256] = f2bf(s1 - bf2f(h1));
  } else {
    if (t < 128) {
      float s = cvec[t];
      for (int d = 0; d < 128; ++d) s += S[t * 128 + d] * bpre[d];
      uv[t] = s;
    }
    __syncthreads();
    for (int o = t; o < 512; o += 256) {
      float s = bpost[o];
      for (int e = 0; e < 128; ++e) s += Wpost[o * 128 + e] * uv[e];
      beff[o] = s;
    }
  }
}

// ---------------------------------------------------------------------------
// out[4096,512] = inp @ Weff^T + beff. M=4096,N=512,K=512, split bf16.
// ---------------------------------------------------------------------------
__global__ __launch_bounds__(256) void final_gemm(
    const unsigned short* __restrict__ Ihi, const unsigned short* __restrict__ Ilo,
    const unsigned short* __restrict__ Whi, const unsigned short* __restrict__ Wlo,
    const float* __restrict__ beff, float* __restrict__ out) {
  __shared__ __align__(16) unsigned short Is_hi[64][40], Is_lo[64][40];
  __shared__ __align__(16) unsigned short Ws_hi[128][40], Ws_lo[128][40];
  const int t = threadIdx.x;
  const int mb = blockIdx.x, nb = blockIdx.y;
  const int w = t >> 6, lane = t & 63;
  const int r16 = lane & 15, q = lane >> 4;

  f32x4 acc[4][2];
#pragma unroll
  for (int x = 0; x < 4; ++x)
#pragma unroll
    for (int y = 0; y < 2; ++y) acc[x][y] = (f32x4){0.f, 0.f, 0.f, 0.f};

  for (int kc = 0; kc < 16; ++kc) {
    const int k0 = kc * 32;
#pragma unroll
    for (int rpt = 0; rpt < 6; ++rpt) {
      int slot = t + rpt * 256;
      if (slot < 512) {
        int arr = slot >> 8, s = slot & 255;
        int row = s >> 2, off = (s & 3) * 8;
        const unsigned short* src = arr ? Ilo : Ihi;
        unsigned short* dst = arr ? &Is_lo[row][off] : &Is_hi[row][off];
        *(uint4*)dst = *(const uint4*)(src + (mb * 64 + row) * 512 + k0 + off);
      } else {
        int s = slot - 512;
        int arr = s >> 9, s2 = s & 511;
        int row = s2 >> 2, off = (s2 & 3) * 8;
        const unsigned short* src = arr ? Wlo : Whi;
        unsigned short* dst = arr ? &Ws_lo[row][off] : &Ws_hi[row][off];
        *(uint4*)dst = *(const uint4*)(src + (nb * 128 + row) * 512 + k0 + off);
      }
    }
    __syncthreads();

    bf16x8 bh0 = __builtin_bit_cast(bf16x8, *(const uint4*)&Ws_hi[w * 32 + r16][q * 8]);
    bf16x8 bl0 = __builtin_bit_cast(bf16x8, *(const uint4*)&Ws_lo[w * 32 + r16][q * 8]);
    bf16x8 bh1 = __builtin_bit_cast(bf16x8, *(const uint4*)&Ws_hi[w * 32 + 16 + r16][q * 8]);
    bf16x8 bl1 = __builtin_bit_cast(bf16x8, *(const uint4*)&Ws_lo[w * 32 + 16 + r16][q * 8]);
#pragma unroll
    for (int mt = 0; mt < 4; ++mt) {
      bf16x8 ah = __builtin_bit_cast(bf16x8, *(const uint4*)&Is_hi[mt * 16 + r16][q * 8]);
      bf16x8 al = __builtin_bit_cast(bf16x8, *(const uint4*)&Is_lo[mt * 16 + r16][q * 8]);
      acc[mt][0] = mfma16(ah, bh0, acc[mt][0]);
      acc[mt][0] = mfma16(al, bh0, acc[mt][0]);
      acc[mt][0] = mfma16(ah, bl0, acc[mt][0]);
      acc[mt][1] = mfma16(ah, bh1, acc[mt][1]);
      acc[mt][1] = mfma16(al, bh1, acc[mt][1]);
      acc[mt][1] = mfma16(ah, bl1, acc[mt][1]);
    }
    __syncthreads();
  }

#pragma unroll
  for (int mt = 0; mt < 4; ++mt)
#pragma unroll
    for (int nt = 0; nt < 2; ++nt) {
      int n = nb * 128 + w * 32 + nt * 16 + r16;
      float bv = beff[n];
#pragma unroll
      for (int r = 0; r < 4; ++r) {
        int m = mb * 64 + mt * 16 + q * 4 + r;
        out[m * 512 + n] = acc[mt][nt][r] + bv;
      }
    }
}

extern "C" void kernel_launch(void* const* d_in, const int* in_sizes, int n_in,
                              void* d_out, int out_size, void* d_ws, size_t ws_size,
                              hipStream_t stream) {
  const float* inp   = (const float*)d_in[0];
  const float* Wpre  = (const float*)d_in[1];
  const float* bpre  = (const float*)d_in[2];
  const float* W     = (const float*)d_in[3];
  const float* bl    = (const float*)d_in[4];
  const float* life  = (const float*)d_in[5];
  const float* Wpost = (const float*)d_in[6];
  const float* bpost = (const float*)d_in[7];
  float* out = (float*)d_out;

  char* p = (char*)d_ws;
  auto alloc = [&](size_t bytes) {
    char* r = p;
    p += (bytes + 255) & ~(size_t)255;
    return r;
  };
  unsigned short* Ahi  = (unsigned short*)alloc((size_t)ND * ND * 2);
  unsigned short* Alo  = (unsigned short*)alloc((size_t)ND * ND * 2);
  unsigned short* QAhi = (unsigned short*)alloc((size_t)MT * ND * 2);
  unsigned short* QAlo = (unsigned short*)alloc((size_t)MT * ND * 2);
  unsigned short* QBhi = (unsigned short*)alloc((size_t)MT * ND * 2);
  unsigned short* QBlo = (unsigned short*)alloc((size_t)MT * ND * 2);
  float* beta = (float*)alloc(ND * 4);
  float* S    = (float*)alloc(128 * 128 * 4);
  float* cvec = (float*)alloc(128 * 4);
  unsigned short* Whi = (unsigned short*)alloc(512 * 512 * 2);
  unsigned short* Wlo = (unsigned short*)alloc(512 * 512 * 2);
  float* beff = (float*)alloc(512 * 4);
  unsigned short* Ihi = (unsigned short*)alloc((size_t)4096 * 512 * 2);
  unsigned short* Ilo = (unsigned short*)alloc((size_t)4096 * 512 * 2);

  prep_kernel<<<3136, 256, 0, stream>>>(W, life, inp, bl, Ahi, Alo, Ihi, Ilo,
                                        QAhi, QAlo, beta);

  // steps t=2..9 (8 full steps), ping-pong QA <-> QB; result lands in QA
  const unsigned short *qh = QAhi, *ql = QAlo;
  unsigned short *oh = QBhi, *ol = QBlo;
  for (int i = 0; i < 8; ++i) {
    step_full<<<128, 768, 0, stream>>>(Ahi, Alo, qh, ql, beta, oh, ol);
    const unsigned short* th = qh; qh = oh; oh = (unsigned short*)th;
    const unsigned short* tl = ql; ql = ol; ol = (unsigned short*)tl;
  }
  // step t=10 restricted to n in [1920,2048): writes S + cvec directly
  step_last<<<dim3(8, 9), 256, 0, stream>>>(Ahi, Alo, qh, ql, beta, S, cvec);

  tail_fused<<<513, 256, 0, stream>>>(S, cvec, Wpre, bpre, Wpost, bpost,
                                      Whi, Wlo, beff);

  final_gemm<<<dim3(64, 4), 256, 0, stream>>>(Ihi, Ilo, Whi, Wlo, beff, out);
}